// Round 1
// 457.011 us; speedup vs baseline: 1.1011x; 1.1011x over previous
//
#include <hip/hip_runtime.h>
#include <cstddef>
#include <cstdint>

#define BHN 128
#define NSEQ 4096
#define EPSF 1e-6f

constexpr int K2_S = 8;
constexpr int K2_ROWS = NSEQ / K2_S;        // 512
constexpr int K2_TILE = 64;
constexpr int K2_TILES = K2_ROWS / K2_TILE; // 8

// ---------------------------------------------------------------------------
// Kernel 2: per-(bh, n-split) partial ctx[d][e] = sum_n exp(k[n,d]) * v[n,e]
// and partial colsum[d] = sum_n exp(k[n,d]). Deterministic (no atomics):
// partials written to scratch, reduced by k2_reduce.
// ---------------------------------------------------------------------------
__global__ __launch_bounds__(256, 4)
void k2_partial_ctx(const float* __restrict__ K, const float* __restrict__ V,
                    float* __restrict__ part_ctx, float* __restrict__ part_cs)
{
    __shared__ __align__(16) float ke[K2_TILE * 64];
    __shared__ __align__(16) float vs[K2_TILE * 64];

    const int bh  = blockIdx.x;
    const int s   = blockIdx.y;
    const int tid = threadIdx.x;
    const int w    = tid >> 6;
    const int lane = tid & 63;
    const int l8   = lane & 7;
    const int h8   = lane >> 3;

    const float4* Kg = (const float4*)(K + ((size_t)bh * NSEQ + (size_t)s * K2_ROWS) * 64);
    const float4* Vg = (const float4*)(V + ((size_t)bh * NSEQ + (size_t)s * K2_ROWS) * 64);

    float acc[8][8];
    #pragma unroll
    for (int i = 0; i < 8; ++i)
        #pragma unroll
        for (int j = 0; j < 8; ++j) acc[i][j] = 0.f;
    float cs[8];
    #pragma unroll
    for (int i = 0; i < 8; ++i) cs[i] = 0.f;

    for (int t = 0; t < K2_TILES; ++t) {
        const float4* kt = Kg + t * (K2_TILE * 16);
        const float4* vt = Vg + t * (K2_TILE * 16);
        float4* ke4 = (float4*)ke;
        float4* vs4 = (float4*)vs;
        #pragma unroll
        for (int p = 0; p < 4; ++p) {
            const int f = tid + p * 256;
            float4 kq = kt[f];
            kq.x = __expf(kq.x);
            kq.y = __expf(kq.y);
            kq.z = __expf(kq.z);
            kq.w = __expf(kq.w);
            ke4[f] = kq;
            vs4[f] = vt[f];
        }
        __syncthreads();
        const float4* keR = (const float4*)ke;
        const float4* vsR = (const float4*)vs;
        #pragma unroll
        for (int nn = 0; nn < 16; ++nn) {
            const int n = w * 16 + nn;               // each wave owns 16 rows
            float4 a0 = keR[n * 16 + h8];            // d = 4*h8 + i
            float4 a1 = keR[n * 16 + 8 + h8];        // d = 32 + 4*h8 + i
            float4 b0 = vsR[n * 16 + l8];            // e = 4*l8 + j
            float4 b1 = vsR[n * 16 + 8 + l8];        // e = 32 + 4*l8 + j
            float a[8] = {a0.x, a0.y, a0.z, a0.w, a1.x, a1.y, a1.z, a1.w};
            float b[8] = {b0.x, b0.y, b0.z, b0.w, b1.x, b1.y, b1.z, b1.w};
            #pragma unroll
            for (int i = 0; i < 8; ++i) cs[i] += a[i];
            #pragma unroll
            for (int i = 0; i < 8; ++i)
                #pragma unroll
                for (int j = 0; j < 8; ++j)
                    acc[i][j] = fmaf(a[i], b[j], acc[i][j]);
        }
        __syncthreads();
    }

    // ---- cross-wave reduction in LDS (vs: 4096-float ctx buf; ke[0..63]: colsum)
    float* red   = vs;
    float* redcs = ke;
    for (int wv = 0; wv < 4; ++wv) {
        if (w == wv) {
            #pragma unroll
            for (int i = 0; i < 8; ++i) {
                const int d = (i < 4) ? (4 * h8 + i) : (32 + 4 * h8 + (i - 4));
                #pragma unroll
                for (int ej = 0; ej < 2; ++ej) {
                    float4* dst = (float4*)&red[d * 64 + ej * 32 + 4 * l8];
                    float4 vv = make_float4(acc[i][4*ej+0], acc[i][4*ej+1],
                                            acc[i][4*ej+2], acc[i][4*ej+3]);
                    if (wv == 0) {
                        *dst = vv;
                    } else {
                        float4 o = *dst;
                        o.x += vv.x; o.y += vv.y; o.z += vv.z; o.w += vv.w;
                        *dst = o;
                    }
                }
                if (l8 == 0) {
                    if (wv == 0) redcs[d] = cs[i];
                    else         redcs[d] += cs[i];
                }
            }
        }
        __syncthreads();
    }

    // ---- store partials (coalesced)
    float4* pc = (float4*)(part_ctx + (size_t)(bh * K2_S + s) * 4096);
    const float4* red4 = (const float4*)red;
    #pragma unroll
    for (int p = 0; p < 4; ++p) {
        const int f = tid + p * 256;
        pc[f] = red4[f];
    }
    if (tid < 16) {
        ((float4*)(part_cs + (size_t)(bh * K2_S + s) * 64))[tid] =
            ((const float4*)redcs)[tid];
    }
}

// ---------------------------------------------------------------------------
// Kernel 2b: reduce the 8 partials, finalize ctxf = raw / (colsum*(1+eps))
// ---------------------------------------------------------------------------
__global__ __launch_bounds__(256)
void k2_reduce(const float* __restrict__ part_ctx, const float* __restrict__ part_cs,
               float* __restrict__ ctxf)
{
    __shared__ float inv_cs[64];
    const int bh  = blockIdx.x;
    const int tid = threadIdx.x;
    if (tid < 64) {
        float c = 0.f;
        #pragma unroll
        for (int s = 0; s < K2_S; ++s)
            c += part_cs[(size_t)(bh * K2_S + s) * 64 + tid];
        inv_cs[tid] = 1.0f / (c * (1.0f + EPSF));
    }
    __syncthreads();
    const float4* pc = (const float4*)(part_ctx + (size_t)bh * K2_S * 4096);
    float4* cf = (float4*)(ctxf + (size_t)bh * 4096);
    const int f = blockIdx.y * 256 + tid;   // 0..1023 float4s
    float4 sum = make_float4(0.f, 0.f, 0.f, 0.f);
    #pragma unroll
    for (int s = 0; s < K2_S; ++s) {
        float4 x = pc[s * 1024 + f];
        sum.x += x.x; sum.y += x.y; sum.z += x.z; sum.w += x.w;
    }
    const float inv = inv_cs[f >> 4];       // d = (4*f)/64
    sum.x *= inv; sum.y *= inv; sum.z *= inv; sum.w *= inv;
    cf[f] = sum;
}

// ---------------------------------------------------------------------------
// Kernel 3: out[n][e] = (sum_d exp(q[n,d]) * ctxf[d][e]) / rowsum[n]
//
// Rewrite vs previous round: 256-thread blocks (4 waves, was 2) at the same
// ~51 KB LDS -> 12 waves/CU resident (was ~5). Stride-68 q-staging keeps row
// bases 16B-aligned so the compute loop reads a-fragments as ds_read_b128;
// row interleave (row = 32w + 8i + h8) puts the 8 h8-groups on bank offsets
// {0,4,...,28} -> conflict-free.
// ---------------------------------------------------------------------------
constexpr int K3_ROWS  = 128;
constexpr int QSTRIDE  = 68;   // 64 + 4 pad: keeps float4 alignment per row

__global__ __launch_bounds__(256, 3)
void k3_out(const float* __restrict__ Q, const float* __restrict__ ctxf,
            float* __restrict__ out)
{
    __shared__ __align__(16) float qe[K3_ROWS * QSTRIDE]; // 34 KB
    __shared__ __align__(16) float ctx_s[4096];           // 16 KB
    __shared__ float rs[K3_ROWS];

    const int bh  = blockIdx.x;
    const int n0  = blockIdx.y * K3_ROWS;
    const int tid = threadIdx.x;
    const int w    = tid >> 6;      // wave 0..3, each owns 32 rows
    const int lane = tid & 63;
    const int l8   = lane & 7;
    const int h8   = lane >> 3;

    // stage ctx (16 KB, 1024 float4s)
    {
        const float4* cg = (const float4*)(ctxf + (size_t)bh * 4096);
        float4* cs4 = (float4*)ctx_s;
        #pragma unroll
        for (int p = 0; p < 4; ++p)
            cs4[tid + p * 256] = cg[tid + p * 256];
    }
    // stage exp(q) + row sums (coalesced: 4 consecutive rows per wave-instr)
    {
        const float4* qg = (const float4*)(Q + ((size_t)bh * NSEQ + n0) * 64);
        const int rgrp = tid >> 4;   // 0..15
        const int c4   = tid & 15;
        #pragma unroll
        for (int p = 0; p < 8; ++p) {
            const int rr = p * 16 + rgrp;
            float4 x = qg[rr * 16 + c4];
            x.x = __expf(x.x); x.y = __expf(x.y);
            x.z = __expf(x.z); x.w = __expf(x.w);
            float ssum = x.x + x.y + x.z + x.w;
            ssum += __shfl_xor(ssum, 1);
            ssum += __shfl_xor(ssum, 2);
            ssum += __shfl_xor(ssum, 4);
            ssum += __shfl_xor(ssum, 8);
            if (c4 == 0) rs[rr] = ssum;
            *(float4*)(qe + rr * QSTRIDE + 4 * c4) = x;
        }
    }
    __syncthreads();

    // row interleave: 8 h8-groups hit distinct bank quads (68*h8 % 32 = 4*h8)
    int rowi[4];
    #pragma unroll
    for (int i = 0; i < 4; ++i) rowi[i] = 32 * w + 8 * i + h8;

    float acc[4][8];
    #pragma unroll
    for (int i = 0; i < 4; ++i)
        #pragma unroll
        for (int j = 0; j < 8; ++j) acc[i][j] = 0.f;

    for (int dc = 0; dc < 64; dc += 4) {
        float a[4][4];
        #pragma unroll
        for (int i = 0; i < 4; ++i) {
            float4 aq = *(const float4*)(qe + rowi[i] * QSTRIDE + dc);
            a[i][0] = aq.x; a[i][1] = aq.y; a[i][2] = aq.z; a[i][3] = aq.w;
        }
        float b[4][8];
        #pragma unroll
        for (int dd = 0; dd < 4; ++dd) {
            float4 b0 = *(const float4*)(ctx_s + (dc + dd) * 64 + 4 * l8);
            float4 b1 = *(const float4*)(ctx_s + (dc + dd) * 64 + 32 + 4 * l8);
            b[dd][0] = b0.x; b[dd][1] = b0.y; b[dd][2] = b0.z; b[dd][3] = b0.w;
            b[dd][4] = b1.x; b[dd][5] = b1.y; b[dd][6] = b1.z; b[dd][7] = b1.w;
        }
        #pragma unroll
        for (int dd = 0; dd < 4; ++dd)
            #pragma unroll
            for (int i = 0; i < 4; ++i)
                #pragma unroll
                for (int j = 0; j < 8; ++j)
                    acc[i][j] = fmaf(a[i][dd], b[dd][j], acc[i][j]);
    }

    float4* og = (float4*)(out + ((size_t)bh * NSEQ + n0) * 64);
    #pragma unroll
    for (int i = 0; i < 4; ++i) {
        const float inv = 1.0f / rs[rowi[i]];
        #pragma unroll
        for (int ej = 0; ej < 2; ++ej) {
            float4 vv = make_float4(acc[i][4*ej+0]*inv, acc[i][4*ej+1]*inv,
                                    acc[i][4*ej+2]*inv, acc[i][4*ej+3]*inv);
            og[rowi[i] * 16 + ej * 8 + l8] = vv;
        }
    }
}

// ---------------------------------------------------------------------------
extern "C" void kernel_launch(void* const* d_in, const int* in_sizes, int n_in,
                              void* d_out, int out_size, void* d_ws, size_t ws_size,
                              hipStream_t stream)
{
    const float* q = (const float*)d_in[0];
    const float* k = (const float*)d_in[1];
    const float* v = (const float*)d_in[2];
    float* out = (float*)d_out;

    // d_out doubles as scratch for the 16.8 MB ctx partials: k2_reduce fully
    // consumes them before k3 overwrites d_out (stream-ordered dispatches).
    float* part_ctx = (float*)d_out;                 // 1024 * 4096 floats
    float* part_cs  = (float*)d_ws;                  // 1024 * 64 floats
    float* ctxf     = part_cs + (size_t)1024 * 64;   // 128 * 4096 floats

    k2_partial_ctx<<<dim3(BHN, K2_S), 256, 0, stream>>>(k, v, part_ctx, part_cs);
    k2_reduce<<<dim3(BHN, 4), 256, 0, stream>>>(part_ctx, part_cs, ctxf);
    k3_out<<<dim3(BHN, NSEQ / K3_ROWS), 256, 0, stream>>>(q, ctxf, out);
}